// Round 4
// baseline (6049.495 us; speedup 1.0000x reference)
//
#include <hip/hip_runtime.h>

// SparseConv3d rulebook scatter-GEMM, MI355X (gfx950)
// R4: counting-sort rules into (k, 256-row output tile) bins, then
// implicit-GEMM gather: bf16 MFMA 16x16x32, A = gathered x rows (natural
// fragment layout, 16B/lane), B = W[k] built in-register per bin, C
// scattered into LDS tile via ds_add. Overflow-exact via fixup kernel.

#define K3    27
#define RULES 1000000
#define CIN   32
#define COUT  32
#define NIN   2000000
#define NOUT  2000000
#define TR    256
#define NT    ((NOUT + TR - 1) / TR)   // 7813 tiles
#define NBINS (K3 * NT)                // 210951 bins
#define CAPB  256                      // capacity per bin (avg 128)
#define OVFCAP 4096
#define SCAN_CHUNK 2048
#define NSCAN ((NBINS + SCAN_CHUNK - 1) / SCAN_CHUNK)  // 104

typedef float f32x4 __attribute__((ext_vector_type(4)));
typedef short bf16x8 __attribute__((ext_vector_type(8)));
typedef unsigned short us8 __attribute__((ext_vector_type(8)));

union BF8 {
  bf16x8 v;
  unsigned short u[8];
};

static __device__ inline unsigned short f2bf(float f) {
  unsigned u = __builtin_bit_cast(unsigned, f);
  u += 0x7fffu + ((u >> 16) & 1u);   // RNE
  return (unsigned short)(u >> 16);
}

// ---------------- x -> bf16 conversion ----------------
__global__ __launch_bounds__(256) void xcvt_kernel(
    const float* __restrict__ x, unsigned short* __restrict__ xbf) {
  const size_t n8 = (size_t)NIN * CIN / 8;
  const size_t stride = (size_t)gridDim.x * 256;
  for (size_t i = (size_t)blockIdx.x * 256 + threadIdx.x; i < n8; i += stride) {
    const f32x4* p = reinterpret_cast<const f32x4*>(x + i * 8);
    const f32x4 a = p[0], b = p[1];
    us8 o;
    o[0] = f2bf(a[0]); o[1] = f2bf(a[1]); o[2] = f2bf(a[2]); o[3] = f2bf(a[3]);
    o[4] = f2bf(b[0]); o[5] = f2bf(b[1]); o[6] = f2bf(b[2]); o[7] = f2bf(b[3]);
    *reinterpret_cast<us8*>(xbf + i * 8) = o;
  }
}

// ---------------- capacity-binned single-pass place ----------------
__global__ __launch_bounds__(256) void place_cap_kernel(
    const int* __restrict__ in_inds, const int* __restrict__ out_inds,
    int* __restrict__ cnt, unsigned* __restrict__ entries,
    int* __restrict__ ovfc, unsigned* __restrict__ ovf) {
  const int k = blockIdx.y;
  const int e = blockIdx.x * 256 + threadIdx.x;
  if (e >= RULES) return;
  const size_t idx = (size_t)k * RULES + e;
  const int oi = out_inds[idx];
  const int ii = in_inds[idx];
  const int bin = k * NT + (oi >> 8);
  const int pos = atomicAdd(&cnt[bin], 1);
  if (pos < CAPB) {
    entries[(size_t)bin * CAPB + pos] =
        ((unsigned)ii << 8) | (unsigned)(oi & 255);
  } else {
    const int op = atomicAdd(ovfc, 1);
    if (op < OVFCAP) {
      ovf[op * 2] = (unsigned)ii;
      ovf[op * 2 + 1] = (unsigned)oi | ((unsigned)k << 21);
    }
  }
}

// ---------------- fixup for (expected-zero) bin overflow ----------------
__global__ __launch_bounds__(256) void fixup_kernel(
    const float* __restrict__ x, const float* __restrict__ weights,
    const int* __restrict__ ovfc, const unsigned* __restrict__ ovf,
    float* __restrict__ out) {
  const int m = min(*ovfc, OVFCAP);
  const int total = m * 32;
  for (int idx = blockIdx.x * 256 + threadIdx.x; idx < total;
       idx += gridDim.x * 256) {
    const int rr = idx >> 5, c = idx & 31;
    const unsigned ii = ovf[rr * 2];
    const unsigned w1 = ovf[rr * 2 + 1];
    const unsigned oi = w1 & 0x1FFFFFu;
    const int k = (int)(w1 >> 21);
    const float* xr = x + (size_t)ii * CIN;
    const float* wk = weights + (size_t)k * CIN * COUT;
    float acc = 0.f;
#pragma unroll
    for (int i = 0; i < CIN; ++i) acc += xr[i] * wk[i * COUT + c];
    atomicAdd(&out[(size_t)oi * COUT + c], acc);
  }
}

// ---------------- exact (hist+scan) variant ----------------
__global__ __launch_bounds__(256) void hist_kernel(
    const int* __restrict__ out_inds, int* __restrict__ cnt) {
  const int k = blockIdx.y;
  const int e = blockIdx.x * 256 + threadIdx.x;
  if (e < RULES) {
    const int oi = out_inds[(size_t)k * RULES + e];
    atomicAdd(&cnt[k * NT + (oi >> 8)], 1);
  }
}

__global__ __launch_bounds__(256) void scan1_kernel(
    const int* __restrict__ cnt, int* __restrict__ offs,
    int* __restrict__ partials) {
  __shared__ int sd[256];
  const int t = threadIdx.x;
  const int base = blockIdx.x * SCAN_CHUNK + t * 8;
  int v[8];
  int s = 0;
#pragma unroll
  for (int i = 0; i < 8; ++i) {
    const int idx = base + i;
    v[i] = (idx < NBINS) ? cnt[idx] : 0;
    s += v[i];
  }
  sd[t] = s;
  __syncthreads();
  const int own = s;
  for (int d = 1; d < 256; d <<= 1) {
    const int xx = (t >= d) ? sd[t - d] : 0;
    __syncthreads();
    sd[t] += xx;
    __syncthreads();
  }
  const int excl = sd[t] - own;
  if (t == 255) partials[blockIdx.x] = sd[255];
  int run = excl;
#pragma unroll
  for (int i = 0; i < 8; ++i) {
    const int idx = base + i;
    if (idx < NBINS) offs[idx] = run;
    run += v[i];
  }
}

__global__ __launch_bounds__(256) void scan2_kernel(int* __restrict__ partials) {
  __shared__ int sd[256];
  const int t = threadIdx.x;
  const int own = (t < NSCAN) ? partials[t] : 0;
  sd[t] = own;
  __syncthreads();
  for (int d = 1; d < 256; d <<= 1) {
    const int xx = (t >= d) ? sd[t - d] : 0;
    __syncthreads();
    sd[t] += xx;
    __syncthreads();
  }
  if (t < NSCAN) partials[t] = sd[t] - own;  // exclusive
}

__global__ __launch_bounds__(256) void scan3_kernel(
    int* __restrict__ offs, const int* __restrict__ partials,
    int* __restrict__ cursor) {
  const int base = blockIdx.x * SCAN_CHUNK + threadIdx.x * 8;
  const int add = partials[blockIdx.x];
#pragma unroll
  for (int i = 0; i < 8; ++i) {
    const int idx = base + i;
    if (idx < NBINS) {
      const int v = offs[idx] + add;
      offs[idx] = v;
      cursor[idx] = v;
    }
  }
}

__global__ __launch_bounds__(256) void place_exact_kernel(
    const int* __restrict__ in_inds, const int* __restrict__ out_inds,
    int* __restrict__ cursor, unsigned* __restrict__ entries) {
  const int k = blockIdx.y;
  const int e = blockIdx.x * 256 + threadIdx.x;
  if (e >= RULES) return;
  const size_t idx = (size_t)k * RULES + e;
  const int oi = out_inds[idx];
  const int ii = in_inds[idx];
  const int bin = k * NT + (oi >> 8);
  const int pos = atomicAdd(&cursor[bin], 1);
  entries[pos] = ((unsigned)ii << 8) | (unsigned)(oi & 255);
}

// ---------------- MFMA gather-compute ----------------
// Block = one 256-row output tile, 4 waves. Wave w handles bins k = w, w+4...
// Per 16-rule group: A-frag = lane reads 16B of x row (rule = lane&15,
// k-chunk = lane>>4); B-frag = W[k] (built per bin, in-register);
// mfma_f32_16x16x32_bf16 x2 (cout halves); C (col=lane&15,
// row=(lane>>4)*4+i [m89]) scattered into LDS tile [257][33] via atomicAdd
// (row 256 = dump row for inactive lanes). Two groups per iter for load ILP.
template <bool CAP, bool XBF>
__global__ __launch_bounds__(256) void gather_mfma_kernel(
    const float* __restrict__ x, const unsigned short* __restrict__ xbf,
    const float* __restrict__ weights, const float* __restrict__ bias,
    const int* __restrict__ offs, const int* __restrict__ cnt,
    const unsigned* __restrict__ entries, float* __restrict__ out) {
  __shared__ float sacc[257 * 33];
  const int bt = blockIdx.x;
  const int tid = threadIdx.x;
  for (int i = tid; i < 257 * 33; i += 256) sacc[i] = 0.f;
  __syncthreads();

  const int wave = tid >> 6;
  const int lane = tid & 63;
  const int lm = lane & 15;   // rule-in-group (A row) / cout (B,C col)
  const int lk = lane >> 4;   // K-chunk selector

  for (int kk = wave; kk < K3; kk += 4) {
    const int bin = kk * NT + bt;
    int n = __builtin_amdgcn_readfirstlane(cnt[bin]);
    if (CAP) n = min(n, CAPB);
    if (n == 0) continue;
    const int s = CAP ? bin * CAPB : __builtin_amdgcn_readfirstlane(offs[bin]);

    // B fragments for W[kk]: b[h].u[j] = bf16(W[kk][lk*8+j][lm+16h])
    const float* __restrict__ wk = weights + (size_t)kk * CIN * COUT;
    BF8 b0, b1;
#pragma unroll
    for (int j = 0; j < 8; ++j) {
      const int krow = lk * 8 + j;
      b0.u[j] = f2bf(wk[krow * COUT + lm]);
      b1.u[j] = f2bf(wk[krow * COUT + lm + 16]);
    }

    for (int base = 0; base < n; base += 32) {
      const int e0 = base + lm;
      const int e1 = e0 + 16;
      const bool v0 = e0 < n;
      const bool v1 = e1 < n;
      const unsigned u0 = v0 ? entries[s + e0] : 0u;
      const unsigned u1 = v1 ? entries[s + e1] : 0u;
      const int ol0 = v0 ? (int)(u0 & 255u) : 256;
      const int ol1 = v1 ? (int)(u1 & 255u) : 256;

      BF8 a0, a1;
      if (XBF) {
        a0.v = *reinterpret_cast<const bf16x8*>(
            xbf + (size_t)(u0 >> 8) * CIN + lk * 8);
        a1.v = *reinterpret_cast<const bf16x8*>(
            xbf + (size_t)(u1 >> 8) * CIN + lk * 8);
      } else {
        const f32x4* p0 =
            reinterpret_cast<const f32x4*>(x + (size_t)(u0 >> 8) * CIN + lk * 8);
        const f32x4* p1 =
            reinterpret_cast<const f32x4*>(x + (size_t)(u1 >> 8) * CIN + lk * 8);
        const f32x4 pa = p0[0], pb = p0[1], qa = p1[0], qb = p1[1];
#pragma unroll
        for (int j = 0; j < 4; ++j) {
          a0.u[j] = f2bf(pa[j]); a0.u[j + 4] = f2bf(pb[j]);
          a1.u[j] = f2bf(qa[j]); a1.u[j + 4] = f2bf(qb[j]);
        }
      }

      f32x4 c00 = {0.f, 0.f, 0.f, 0.f}, c01 = {0.f, 0.f, 0.f, 0.f};
      f32x4 c10 = {0.f, 0.f, 0.f, 0.f}, c11 = {0.f, 0.f, 0.f, 0.f};
      c00 = __builtin_amdgcn_mfma_f32_16x16x32_bf16(a0.v, b0.v, c00, 0, 0, 0);
      c01 = __builtin_amdgcn_mfma_f32_16x16x32_bf16(a0.v, b1.v, c01, 0, 0, 0);
      c10 = __builtin_amdgcn_mfma_f32_16x16x32_bf16(a1.v, b0.v, c10, 0, 0, 0);
      c11 = __builtin_amdgcn_mfma_f32_16x16x32_bf16(a1.v, b1.v, c11, 0, 0, 0);

#pragma unroll
      for (int i = 0; i < 4; ++i) {
        const int r = lk * 4 + i;
        const int o0 = __shfl(ol0, r);
        const int o1 = __shfl(ol1, r);
        atomicAdd(&sacc[o0 * 33 + lm], c00[i]);
        atomicAdd(&sacc[o0 * 33 + lm + 16], c01[i]);
        atomicAdd(&sacc[o1 * 33 + lm], c10[i]);
        atomicAdd(&sacc[o1 * 33 + lm + 16], c11[i]);
      }
    }
  }
  __syncthreads();

  const float4* __restrict__ b4 = reinterpret_cast<const float4*>(bias);
#pragma unroll
  for (int r = 0; r < 8; ++r) {
    const int idx = r * 256 + tid;  // float4 index within tile [0,2048)
    const int row = idx >> 3;
    const int f4c = idx & 7;
    const int grow = bt * TR + row;
    if (grow < NOUT) {
      float4 v;
      v.x = sacc[row * 33 + f4c * 4 + 0];
      v.y = sacc[row * 33 + f4c * 4 + 1];
      v.z = sacc[row * 33 + f4c * 4 + 2];
      v.w = sacc[row * 33 + f4c * 4 + 3];
      const float4 bb = b4[f4c];
      v.x += bb.x; v.y += bb.y; v.z += bb.z; v.w += bb.w;
      reinterpret_cast<float4*>(out)[(size_t)grow * 8 + f4c] = v;
    }
  }
}

// ---------------- last-resort fallback (R1 path) ----------------
__global__ __launch_bounds__(256) void bias_init_kernel(
    float* __restrict__ out, const float* __restrict__ bias) {
  float4 b[8];
#pragma unroll
  for (int j = 0; j < 8; ++j) b[j] = reinterpret_cast<const float4*>(bias)[j];
  const size_t total4 = (size_t)NOUT * COUT / 4;
  const size_t stride = (size_t)gridDim.x * blockDim.x;
  for (size_t i = (size_t)blockIdx.x * blockDim.x + threadIdx.x; i < total4;
       i += stride)
    reinterpret_cast<float4*>(out)[i] = b[i & 7];
}

__global__ __launch_bounds__(256) void scatter_gemm_kernel(
    const float* __restrict__ x, const float* __restrict__ weights,
    const int* __restrict__ in_inds, const int* __restrict__ out_inds,
    float* __restrict__ out) {
  const int k = blockIdx.y;
  const int e = blockIdx.x * 256 + threadIdx.x;
  if (e >= RULES) return;
  const int ii = in_inds[(size_t)k * RULES + e];
  const int oi = out_inds[(size_t)k * RULES + e];
  float xr[CIN];
  const float4* xrow = reinterpret_cast<const float4*>(x + (size_t)ii * CIN);
#pragma unroll
  for (int j = 0; j < 8; ++j) {
    float4 v = xrow[j];
    xr[4 * j] = v.x; xr[4 * j + 1] = v.y; xr[4 * j + 2] = v.z; xr[4 * j + 3] = v.w;
  }
  const float* wk = weights + (size_t)k * CIN * COUT;
  float acc[COUT];
#pragma unroll
  for (int c = 0; c < COUT; ++c) acc[c] = 0.f;
#pragma unroll
  for (int i = 0; i < CIN; ++i) {
    const float xi = xr[i];
#pragma unroll
    for (int c = 0; c < COUT; ++c) acc[c] += xi * wk[i * COUT + c];
  }
#pragma unroll
  for (int c = 0; c < COUT; ++c) atomicAdd(&out[(size_t)oi * COUT + c], acc[c]);
}

static inline size_t align4k(size_t v) { return (v + 4095) & ~(size_t)4095; }

extern "C" void kernel_launch(void* const* d_in, const int* in_sizes, int n_in,
                              void* d_out, int out_size, void* d_ws,
                              size_t ws_size, hipStream_t stream) {
  const float* x        = (const float*)d_in[0];
  const float* weights  = (const float*)d_in[1];
  const float* bias     = (const float*)d_in[2];
  const int*   in_inds  = (const int*)d_in[3];
  const int*   out_inds = (const int*)d_in[4];
  float*       out      = (float*)d_out;
  char*        ws       = (char*)d_ws;

  dim3 rgrid((RULES + 255) / 256, K3);

  // cap-path workspace layout
  const size_t o_cnt = 0;
  const size_t o_ovfc = align4k(o_cnt + (size_t)NBINS * 4);
  const size_t o_ovf = o_ovfc + 4096;
  const size_t o_entries = align4k(o_ovf + (size_t)OVFCAP * 8);
  const size_t o_xbf = align4k(o_entries + (size_t)NBINS * CAPB * 4);
  const size_t REQ_F32 = o_xbf;
  const size_t REQ_BF = o_xbf + (size_t)NIN * CIN * 2;
  const size_t REQ_EXACT = ((size_t)3 * NBINS + 128 + (size_t)K3 * RULES) * 4;

  if (ws_size >= REQ_F32) {
    int* cnt = (int*)(ws + o_cnt);
    int* ovfc = (int*)(ws + o_ovfc);
    unsigned* ovf = (unsigned*)(ws + o_ovf);
    unsigned* entries = (unsigned*)(ws + o_entries);
    unsigned short* xbf = (unsigned short*)(ws + o_xbf);
    const bool BF = ws_size >= REQ_BF;

    hipMemsetAsync(ws, 0, o_ovfc + 4, stream);  // cnt + ovfc
    place_cap_kernel<<<rgrid, 256, 0, stream>>>(in_inds, out_inds, cnt,
                                                entries, ovfc, ovf);
    if (BF) {
      xcvt_kernel<<<2048, 256, 0, stream>>>(x, xbf);
      gather_mfma_kernel<true, true><<<NT, 256, 0, stream>>>(
          x, xbf, weights, bias, nullptr, cnt, entries, out);
    } else {
      gather_mfma_kernel<true, false><<<NT, 256, 0, stream>>>(
          x, nullptr, weights, bias, nullptr, cnt, entries, out);
    }
    fixup_kernel<<<16, 256, 0, stream>>>(x, weights, ovfc, ovf, out);
  } else if (ws_size >= REQ_EXACT) {
    int* cnt      = (int*)d_ws;
    int* offs     = cnt + NBINS;
    int* cursor   = offs + NBINS;
    int* partials = cursor + NBINS;
    unsigned* entries = (unsigned*)(partials + 128);
    hipMemsetAsync(cnt, 0, (size_t)NBINS * sizeof(int), stream);
    hist_kernel<<<rgrid, 256, 0, stream>>>(out_inds, cnt);
    scan1_kernel<<<NSCAN, 256, 0, stream>>>(cnt, offs, partials);
    scan2_kernel<<<1, 256, 0, stream>>>(partials);
    scan3_kernel<<<NSCAN, 256, 0, stream>>>(offs, partials, cursor);
    place_exact_kernel<<<rgrid, 256, 0, stream>>>(in_inds, out_inds, cursor,
                                                  entries);
    gather_mfma_kernel<false, false><<<NT, 256, 0, stream>>>(
        x, nullptr, weights, bias, offs, cnt, entries, out);
  } else {
    bias_init_kernel<<<2048, 256, 0, stream>>>(out, bias);
    scatter_gemm_kernel<<<rgrid, 256, 0, stream>>>(x, weights, in_inds,
                                                   out_inds, out);
  }
}